// Round 15
// baseline (923.586 us; speedup 1.0000x reference)
//
#include <hip/hip_runtime.h>
#include <hip/hip_bf16.h>

// ---------------------------------------------------------------------------
// Qwen2.5-VL decoder layer, MI355X (gfx950)
// B=1, N=1024, D=3584, H=28, KVH=4, HD=128, I=18944
// Round 15: R14 (=R12 best) + QKV GEMM split-K 2 -> 4 (288 blocks, T=14:
// fills the 256 CUs instead of 56%), qkv_reduce_rope sums 4 slabs and reads
// bq/bk/bv directly (pack_bias launch removed).
// ---------------------------------------------------------------------------

#define SEQ   1024
#define DIM   3584
#define NH    28
#define NKVH  4
#define HDIM  128
#define IDIM  18944
#define QKVN  4608    // 3584 q + 512 k + 512 v
#define GUN   37888   // 2*18944

typedef __attribute__((ext_vector_type(8))) __bf16 bf16x8;
typedef __attribute__((ext_vector_type(4))) __bf16 bf16x4;
typedef __attribute__((ext_vector_type(4))) float  f32x4;

// ---------------- workspace layout (bytes) ----------------
static constexpr size_t OFF_WQKVT = 0;                                   // [4608][3584] bf16
static constexpr size_t OFF_WOT   = OFF_WQKVT + (size_t)QKVN*DIM*2;      // [3584][3584] bf16
static constexpr size_t OFF_WGUT  = OFF_WOT   + (size_t)DIM*DIM*2;       // [37888][3584] bf16 (interleaved g/u)
static constexpr size_t OFF_WDT   = OFF_WGUT  + (size_t)GUN*DIM*2;       // [3584][18944] bf16
static constexpr size_t OFF_XB    = OFF_WDT   + (size_t)DIM*IDIM*2;      // [1024][3584] bf16
static constexpr size_t OFF_QKV   = OFF_XB    + (size_t)SEQ*DIM*2;       // [1024][4608] bf16
static constexpr size_t OFF_VT    = OFF_QKV   + (size_t)SEQ*QKVN*2;      // [4][128][1024] bf16
static constexpr size_t OFF_VSUMP = OFF_VT    + (size_t)NKVH*HDIM*SEQ*2; // [4][8][128] f32
static constexpr size_t OFF_VSUM  = OFF_VSUMP + 4*8*128*4;               // [4][128] f32
static constexpr size_t OFF_OB    = OFF_VSUM  + 4*128*4;                 // [1024][3584] bf16
static constexpr size_t OFF_HB    = OFF_OB    + (size_t)SEQ*DIM*2;       // [1024][3584] f32
static constexpr size_t OFF_YB    = OFF_HB    + (size_t)SEQ*DIM*4;       // [1024][3584] bf16
static constexpr size_t OFF_GU    = OFF_YB    + (size_t)SEQ*DIM*2;       // 77.6 MB scratch region
static constexpr size_t OFF_PB    = OFF_GU    + (size_t)SEQ*GUN*2;       // [1024][18944] bf16
// split-K f32 partials live in the (always dead) GU region:
// QKV S=4: 75.5 MB; others <= 58.7 MB; region = 77.6 MB.
static constexpr size_t OFF_PART  = OFF_GU;

// async global->LDS, 16B per lane. lds ptr must be wave-uniform; HW writes
// lane l's 16B to ldsbase + l*16. global ptr is per-lane.
#define GLL16(gp, lp)                                                        \
  __builtin_amdgcn_global_load_lds(                                         \
      (const __attribute__((address_space(1))) void*)(gp),                  \
      (__attribute__((address_space(3))) void*)(lp), 16, 0, 0)

#define BAR    asm volatile("s_barrier" ::: "memory")
#define LGKM0  asm volatile("s_waitcnt lgkmcnt(0)" ::: "memory")
#define VM4    asm volatile("s_waitcnt vmcnt(4)" ::: "memory")

// ---------------- weight transpose + fp32->bf16 ----------------
// mode 0: out row = n.  mode 1/2: interleaved gate/up layout
// (phys row = (n>>4)*32 + (n&15) + (mode==2 ? 16 : 0)).
__global__ __launch_bounds__(256) void transconv_kernel(
    const float* __restrict__ W, __bf16* __restrict__ WT, int K, int N, int mode)
{
  __shared__ __bf16 t[64][72];
  const int tid = threadIdx.x;
  const int k0 = blockIdx.y * 64, n0 = blockIdx.x * 64;
#pragma unroll
  for (int it = 0; it < 4; ++it) {
    int idx = it * 256 + tid;
    int r = idx >> 4, c4 = idx & 15;
    float4 v = *(const float4*)(W + (size_t)(k0 + r) * N + n0 + c4 * 4);
    t[r][c4 * 4 + 0] = (__bf16)v.x;
    t[r][c4 * 4 + 1] = (__bf16)v.y;
    t[r][c4 * 4 + 2] = (__bf16)v.z;
    t[r][c4 * 4 + 3] = (__bf16)v.w;
  }
  __syncthreads();
#pragma unroll
  for (int it = 0; it < 2; ++it) {
    int idx = it * 256 + tid;
    int r = idx >> 3, c8 = idx & 7;
    bf16x8 o;
#pragma unroll
    for (int i = 0; i < 8; ++i) o[i] = t[c8 * 8 + i][r];
    const int nlog = n0 + r;
    const int orow = (mode == 0) ? nlog
                   : ((nlog >> 4) << 5) + ((mode == 2) ? 16 : 0) + (nlog & 15);
    *(bf16x8*)(WT + (size_t)orow * K + k0 + c8 * 8) = o;
  }
}

// ---------------- RMSNorm (fp32 in, bf16 out) ----------------
__global__ __launch_bounds__(256) void rmsnorm_kernel(
    const float* __restrict__ in, const float* __restrict__ w,
    __bf16* __restrict__ out)
{
  const int row = blockIdx.x;
  const int t = threadIdx.x;
  const float* x = in + (size_t)row * DIM;
  float4 v[4];
  float ss = 0.f;
#pragma unroll
  for (int i = 0; i < 4; ++i) {
    int idx = t + i * 256;
    if (idx < 896) {
      v[i] = ((const float4*)x)[idx];
      ss += v[i].x * v[i].x + v[i].y * v[i].y + v[i].z * v[i].z + v[i].w * v[i].w;
    }
  }
#pragma unroll
  for (int m = 1; m < 64; m <<= 1) ss += __shfl_xor(ss, m);
  __shared__ float red[4];
  if ((t & 63) == 0) red[t >> 6] = ss;
  __syncthreads();
  float tot = red[0] + red[1] + red[2] + red[3];
  float rs = rsqrtf(tot / (float)DIM + 1e-6f);
#pragma unroll
  for (int i = 0; i < 4; ++i) {
    int idx = t + i * 256;
    if (idx < 896) {
      float4 wv = ((const float4*)w)[idx];
      bf16x4 o;
      o[0] = (__bf16)(v[i].x * rs * wv.x);
      o[1] = (__bf16)(v[i].y * rs * wv.y);
      o[2] = (__bf16)(v[i].z * rs * wv.z);
      o[3] = (__bf16)(v[i].w * rs * wv.w);
      *(bf16x4*)(out + (size_t)row * DIM + idx * 4) = o;
    }
  }
}

// ---------------- split-K reduce epilogues ---------------------------------
template<int S, bool BF16OUT>
__global__ __launch_bounds__(256) void reduce_kernel(
    const float* __restrict__ part, const float* __restrict__ resid,
    void* __restrict__ out, int N, int MN4)
{
  const int i4 = blockIdx.x * 256 + threadIdx.x;
  if (i4 >= MN4) return;
  const size_t base = (size_t)i4 * 4;
  f32x4 s = *(const f32x4*)(part + base);
#pragma unroll
  for (int k = 1; k < S; ++k)
    s += *(const f32x4*)(part + (size_t)k * MN4 * 4 + base);
  if (resid != nullptr) s += *(const f32x4*)(resid + base);
  if (BF16OUT) {
    bf16x4 o;
#pragma unroll
    for (int j = 0; j < 4; ++j) o[j] = (__bf16)s[j];
    *(bf16x4*)((__bf16*)out + base) = o;
  } else {
    *(f32x4*)((float*)out + base) = s;
  }
}

// ---------------- fused QKV split-K(4) reduce + bias + mRoPE ---------------
// qkv[n][col] = rope( sum4 part + bias ).  grid = SEQ, 256 threads.
// Thread t: head = t>>3 (28 q + 4 k heads), d0 = (t&7)*8 — holds both rope
// halves (d, d+64) in registers. V columns: 2 per thread (sum+bias only).
__global__ __launch_bounds__(256) void qkv_reduce_rope_kernel(
    const float* __restrict__ part, const float* __restrict__ bq,
    const float* __restrict__ bk, const float* __restrict__ bv,
    const float* __restrict__ cosb, const float* __restrict__ sinb,
    __bf16* __restrict__ qkv)
{
  const int n = blockIdx.x;
  const int t = threadIdx.x;
  const size_t rb = (size_t)n * QKVN;
  const size_t slab = (size_t)SEQ * QKVN;

  const int head = t >> 3;
  const int d0 = (t & 7) * 8;
  const int col = (head < NH) ? head * HDIM + d0 : DIM + (head - NH) * HDIM + d0;
  const float* bp = (head < NH) ? (bq + head * HDIM + d0)
                                : (bk + (head - NH) * HDIM + d0);

  float lo[8], hi[8];
#pragma unroll
  for (int j = 0; j < 8; j += 4) {
    f32x4 s0 = *(const f32x4*)(part + rb + col + j);
    f32x4 s1 = *(const f32x4*)(part + rb + col + 64 + j);
#pragma unroll
    for (int k = 1; k < 4; ++k) {
      s0 += *(const f32x4*)(part + (size_t)k * slab + rb + col + j);
      s1 += *(const f32x4*)(part + (size_t)k * slab + rb + col + 64 + j);
    }
    f32x4 bi  = *(const f32x4*)(bp + j);
    f32x4 bi2 = *(const f32x4*)(bp + 64 + j);
#pragma unroll
    for (int i = 0; i < 4; ++i) {
      lo[j + i] = s0[i] + bi[i];
      hi[j + i] = s1[i] + bi2[i];
    }
  }
  bf16x8 olo, ohi;
#pragma unroll
  for (int j = 0; j < 8; ++j) {
    const int d = d0 + j;
    const int src = (d < 16) ? 0 : (d < 40) ? 1 : 2;   // same src for d and d+64
    const float* cb = cosb + ((size_t)src * SEQ + n) * HDIM;
    const float* sb = sinb + ((size_t)src * SEQ + n) * HDIM;
    const float c0 = cb[d], s0 = sb[d];
    const float c1 = cb[d + 64], s1 = sb[d + 64];
    olo[j] = (__bf16)(lo[j] * c0 - hi[j] * s0);
    ohi[j] = (__bf16)(hi[j] * c1 + lo[j] * s1);
  }
  *(bf16x8*)(qkv + rb + col) = olo;
  *(bf16x8*)(qkv + rb + col + 64) = ohi;

  // v: cols 4096 + 2t, 2t+1 (no rope)
  {
    const int vc = 4096 + t * 2;
    float2 s = *(const float2*)(part + rb + vc);
#pragma unroll
    for (int k = 1; k < 4; ++k) {
      float2 a = *(const float2*)(part + (size_t)k * slab + rb + vc);
      s.x += a.x; s.y += a.y;
    }
    qkv[rb + vc]     = (__bf16)(s.x + bv[t * 2]);
    qkv[rb + vc + 1] = (__bf16)(s.y + bv[t * 2 + 1]);
  }
}

// ---------------- fused split-K(4) reduce + residual + RMSNorm -------------
__global__ __launch_bounds__(256) void reduce_rms_kernel(
    const float* __restrict__ part, const float* __restrict__ resid,
    const float* __restrict__ w, float* __restrict__ hout,
    __bf16* __restrict__ yout)
{
  const int row = blockIdx.x;
  const int t = threadIdx.x;
  const size_t base = (size_t)row * DIM;
  const size_t slab = (size_t)SEQ * DIM;
  f32x4 v[4];
  float ss = 0.f;
#pragma unroll
  for (int i = 0; i < 4; ++i) {
    int idx = t + i * 256;
    if (idx < 896) {
      f32x4 s = *(const f32x4*)(part + base + idx * 4);
      s += *(const f32x4*)(part + slab + base + idx * 4);
      s += *(const f32x4*)(part + 2 * slab + base + idx * 4);
      s += *(const f32x4*)(part + 3 * slab + base + idx * 4);
      s += *(const f32x4*)(resid + base + idx * 4);
      v[i] = s;
      ss += s[0] * s[0] + s[1] * s[1] + s[2] * s[2] + s[3] * s[3];
      *(f32x4*)(hout + base + idx * 4) = s;
    }
  }
#pragma unroll
  for (int m = 1; m < 64; m <<= 1) ss += __shfl_xor(ss, m);
  __shared__ float red[4];
  if ((t & 63) == 0) red[t >> 6] = ss;
  __syncthreads();
  float tot = red[0] + red[1] + red[2] + red[3];
  float rs = rsqrtf(tot / (float)DIM + 1e-6f);
#pragma unroll
  for (int i = 0; i < 4; ++i) {
    int idx = t + i * 256;
    if (idx < 896) {
      f32x4 wv = *(const f32x4*)(w + idx * 4);
      bf16x4 o;
#pragma unroll
      for (int j = 0; j < 4; ++j) o[j] = (__bf16)(v[i][j] * rs * wv[j]);
      *(bf16x4*)(yout + base + idx * 4) = o;
    }
  }
}

// ---------------- 256x256 8-phase GEMM, 1 barrier per phase ----------------
// Interval: {LGKM0; MFMA(q); RD(q+1); STG; [VM4 then RD at gates]; BAR}.
// Same-interval STG/RD regions disjoint (verified per phase); VM4 gates
// drain exactly the to-be-read tile (newest-4 = the two just-issued pairs).
// EPI 0: gate/up interleaved -> silu(g)*u -> bf16 [M][N/2] out.
// EPI 1: f32 split-K partial out (OUT + ks*M*N).
template<int EPI>
__global__ __launch_bounds__(512, 1) void gemm256_kernel(
    const __bf16* __restrict__ A, const __bf16* __restrict__ BT,
    void* __restrict__ OUT, int M, int N, int K, int Kc, int gridY)
{
  __shared__ int4 lds4[8192];            // 128 KB
  char* ldsc = (char*)lds4;
  const int tid = threadIdx.x;
  const int l = tid & 63, w = tid >> 6;
  const int wr = w >> 2, wc = w & 3;
  const int lg = l >> 4, lc = l & 15;

  const int nwg = gridDim.x;
  const int bq8 = nwg >> 3, br8 = nwg & 7;
  const int xcd = blockIdx.x & 7, bidx = blockIdx.x >> 3;
  const int wg = (xcd < br8 ? xcd * (bq8 + 1) : br8 * (bq8 + 1) + (xcd - br8) * bq8) + bidx;
  const int ntn = N >> 8;
  const int wg2 = wg / gridY;
  const int row0 = (wg % gridY) * 256;
  const int col0 = (wg2 % ntn) * 256;
  const int ks_ = wg2 / ntn;
  const int kbase = ks_ * Kc;

  size_t aoffj[2], boffj[2];
  int dstj[2];
#pragma unroll
  for (int j = 0; j < 2; ++j) {
    const int c = (j * 8 + w) * 64 + l;
    const int r = c >> 3, p = c & 7;
    const int b = p ^ (r & 7);
    aoffj[j] = (size_t)(row0 + r) * K + kbase + b * 8;
    boffj[j] = (size_t)(col0 + r) * K + kbase + b * 8;
    dstj[j] = (j * 8 + w) * 1024;
  }

#define STG_A(U, KT, BUFB) do {                                              \
    GLL16(A + aoffj[0] + (size_t)(U) * 128 * K + (size_t)(KT) * 64,          \
          ldsc + (BUFB) + (U) * 16384 + dstj[0]);                            \
    GLL16(A + aoffj[1] + (size_t)(U) * 128 * K + (size_t)(KT) * 64,          \
          ldsc + (BUFB) + (U) * 16384 + dstj[1]); } while (0)
#define STG_B(U, KT, BUFB) do {                                              \
    GLL16(BT + boffj[0] + (size_t)(U) * 128 * K + (size_t)(KT) * 64,         \
          ldsc + (BUFB) + 32768 + (U) * 16384 + dstj[0]);                    \
    GLL16(BT + boffj[1] + (size_t)(U) * 128 * K + (size_t)(KT) * 64,         \
          ldsc + (BUFB) + 32768 + (U) * 16384 + dstj[1]); } while (0)

  const int sw = lc & 7;
  const int rdA = (wr * 128 + lc) * 128;
  const int rdB = 32768 + (wc * 64 + lc) * 128;
  const int sk0 = (lg ^ sw) * 16;
  const int sk1 = ((4 | lg) ^ sw) * 16;

  f32x4 acc[8][4] = {};
  bf16x8 af[4][2], bfr[4][2];

#define RD_A4(MH, BUFB) do { _Pragma("unroll")                               \
    for (int mm = 0; mm < 4; ++mm) {                                         \
      af[mm][0] = *(const bf16x8*)(ldsc + (BUFB) + rdA + ((MH) * 4 + mm) * 2048 + sk0); \
      af[mm][1] = *(const bf16x8*)(ldsc + (BUFB) + rdA + ((MH) * 4 + mm) * 2048 + sk1); } } while (0)
#define RD_B2(NL, BUFB) do { _Pragma("unroll")                               \
    for (int nn = 0; nn < 2; ++nn) {                                         \
      bfr[(NL) + nn][0] = *(const bf16x8*)(ldsc + (BUFB) + rdB + ((NL) + nn) * 2048 + sk0); \
      bfr[(NL) + nn][1] = *(const bf16x8*)(ldsc + (BUFB) + rdB + ((NL) + nn) * 2048 + sk1); } } while (0)

#define MFMA16(MH, NL) do { _Pragma("unroll")                                \
    for (int mm = 0; mm < 4; ++mm) { _Pragma("unroll")                       \
      for (int nn = 0; nn < 2; ++nn) {                                       \
        acc[(MH)*4+mm][(NL)+nn] = __builtin_amdgcn_mfma_f32_16x16x32_bf16(   \
            af[mm][0], bfr[(NL)+nn][0], acc[(MH)*4+mm][(NL)+nn], 0, 0, 0);   \
        acc[(MH)*4+mm][(NL)+nn] = __builtin_amdgcn_mfma_f32_16x16x32_bf16(   \
            af[mm][1], bfr[(NL)+nn][1], acc[(MH)*4+mm][(NL)+nn], 0, 0, 0); } } } while (0)

#define DO_MFMA(MH, NL)                                                      \
    __builtin_amdgcn_s_setprio(1); MFMA16(MH, NL);                           \
    __builtin_amdgcn_s_setprio(0)

  // prologue: E(tile0) full + O(tile1) B halves; VM4 drains E (own-wave),
  // BAR makes it block-wide; then prefetch q1(E).
  STG_B(0, 0, 0); STG_B(1, 0, 0); STG_A(0, 0, 0); STG_A(1, 0, 0);
  STG_B(0, 1, 65536); STG_B(1, 1, 65536);
  VM4;
  BAR;
  RD_A4(0, 0); RD_B2(0, 0);

  const int T = Kc >> 6;                 // even for all call sites
#pragma unroll 1
  for (int i = 0; i < (T >> 1); ++i) {
    const int t1 = 2 * i + 1;
    const int se = (2 * i + 2 < T) ? 2 * i + 2 : 2 * i;   // E next (dummy=cur)
    const int so = (2 * i + 3 < T) ? 2 * i + 3 : t1;      // O next
    // I1: MFMA q1(E); read q2(E); stage O.A0(t1)
    LGKM0; DO_MFMA(0, 0); RD_B2(2, 0); STG_A(0, t1, 65536); BAR;
    // I2: MFMA q2(E); read q3(E); stage O.A1(t1)
    LGKM0; DO_MFMA(0, 2); RD_A4(1, 0); STG_A(1, t1, 65536); BAR;
    // I3: MFMA q3(E); stage E.B0(se)   [E.B last read completed at I2 LGKM0]
    LGKM0; DO_MFMA(1, 2); STG_B(0, se, 0); BAR;
    // I4: MFMA q4(E, reg-only); stage E.B1(se); GATE O(t1); read q1(O)
    DO_MFMA(1, 0); STG_B(1, se, 0); VM4; RD_A4(0, 65536); RD_B2(0, 65536); BAR;
    // I5: MFMA q1(O); read q2(O); stage E.A0(se)
    LGKM0; DO_MFMA(0, 0); RD_B2(2, 65536); STG_A(0, se, 0); BAR;
    // I6: MFMA q2(O); read q3(O); stage E.A1(se)
    LGKM0; DO_MFMA(0, 2); RD_A4(1, 65536); STG_A(1, se, 0); BAR;
    // I7: MFMA q3(O); stage O.B0(so)
    LGKM0; DO_MFMA(1, 2); STG_B(0, so, 65536); BAR;
    // I8: MFMA q4(O); stage O.B1(so); GATE E(se); read q1(E next)
    DO_MFMA(1, 0); STG_B(1, so, 65536); VM4; RD_A4(0, 0); RD_B2(0, 0); BAR;
  }
  asm volatile("s_waitcnt vmcnt(0)" ::: "memory");
  LGKM0;                                 // drain trailing prefetch reads

  if (EPI == 0) {
    // interleaved g/u: fragment n even = gate cols, n odd = up cols (same q)
    __bf16* PBo = (__bf16*)OUT;
    const int id = N >> 1;               // 18944
    const int baseq = (col0 + wc * 64) >> 5;
#pragma unroll
    for (int m = 0; m < 8; ++m) {
#pragma unroll
      for (int p = 0; p < 2; ++p) {
        const int gcol = (baseq + p) * 16 + lc;
#pragma unroll
        for (int j = 0; j < 4; ++j) {
          const int row = row0 + wr * 128 + m * 16 + lg * 4 + j;
          const float g = acc[m][2 * p][j];
          const float u = acc[m][2 * p + 1][j];
          const float s = g / (1.f + __expf(-g));
          PBo[(size_t)row * id + gcol] = (__bf16)(s * u);
        }
      }
    }
  } else {
    float* P = (float*)OUT + (size_t)ks_ * M * N;
#pragma unroll
    for (int m = 0; m < 8; ++m)
#pragma unroll
      for (int n = 0; n < 4; ++n)
#pragma unroll
        for (int j = 0; j < 4; ++j)
          P[(size_t)(row0 + wr * 128 + m * 16 + lg * 4 + j) * N
            + (col0 + wc * 64 + n * 16 + lc)] = acc[m][n][j];
  }
#undef STG_A
#undef STG_B
#undef RD_A4
#undef RD_B2
#undef MFMA16
#undef DO_MFMA
}

// ---------------- V transpose [n][d] -> [d][n], plus column sums -----------
__global__ __launch_bounds__(256) void vtrans_kernel(
    const __bf16* __restrict__ qkv, __bf16* __restrict__ vT,
    float* __restrict__ vsump)
{
  __shared__ __bf16 t[128][132];
  const int nt = blockIdx.x, kvh = blockIdx.y;
  const int n0 = nt * 128;
  const int tid = threadIdx.x;
#pragma unroll
  for (int it = 0; it < 8; ++it) {
    int idx = it * 256 + tid;
    int nl = idx >> 4, c8 = idx & 15;
    bf16x8 v = *(const bf16x8*)(qkv + (size_t)(n0 + nl) * QKVN + 4096 + kvh * HDIM + c8 * 8);
#pragma unroll
    for (int i = 0; i < 8; ++i) t[nl][c8 * 8 + i] = v[i];
  }
  __syncthreads();
#pragma unroll
  for (int it = 0; it < 8; ++it) {
    int idx = it * 256 + tid;
    int d = idx >> 4, c8 = idx & 15;
    bf16x8 o;
#pragma unroll
    for (int i = 0; i < 8; ++i) o[i] = t[c8 * 8 + i][d];
    *(bf16x8*)(vT + (size_t)(kvh * HDIM + d) * SEQ + n0 + c8 * 8) = o;
  }
  if (tid < 128) {
    float s = 0.f;
    for (int nl = 0; nl < 128; ++nl) s += (float)t[nl][tid];
    vsump[(size_t)(kvh * 8 + nt) * 128 + tid] = s;
  }
}

__global__ __launch_bounds__(512) void vsum_reduce_kernel(
    const float* __restrict__ vsump, float* __restrict__ vsum)
{
  const int idx = threadIdx.x;
  const int kvh = idx >> 7, d = idx & 127;
  float s = 0.f;
#pragma unroll
  for (int nt = 0; nt < 8; ++nt) s += vsump[(size_t)(kvh * 8 + nt) * 128 + d];
  vsum[idx] = s;
}

// ---------------- attention -------------------------------------------------
__global__ __launch_bounds__(256) void attn_kernel(
    const __bf16* __restrict__ qkv, const __bf16* __restrict__ vT,
    const float* __restrict__ vsum, const int* __restrict__ prune,
    __bf16* __restrict__ o)
{
  __shared__ __bf16 plds[4 * 16 * 40];
  const int tid = threadIdx.x;
  const int l = tid & 63, w = tid >> 6;
  const int h = blockIdx.y;
  const int kvh = h / 7;
  const int qt = blockIdx.x;
  const int qbase = qt * 64 + w * 16;
  const int lg = l >> 4, lc = l & 15;
  __bf16* pw = plds + w * (16 * 40);

  bf16x8 qf[4];
#pragma unroll
  for (int s = 0; s < 4; ++s)
    qf[s] = *(const bf16x8*)(qkv + (size_t)(qbase + lc) * QKVN + h * HDIM + s * 32 + lg * 8);

  f32x4 oacc[8] = {};
  float mrun[4] = {-3e38f, -3e38f, -3e38f, -3e38f};
  float lrun[4] = {0.f, 0.f, 0.f, 0.f};

  const int kbEnd = ((qbase + 15) >> 5) + 1;
  for (int kb = 0; kb < kbEnd; ++kb) {
    f32x4 sacc[2] = {};
#pragma unroll
    for (int s = 0; s < 4; ++s) {
#pragma unroll
      for (int c = 0; c < 2; ++c) {
        bf16x8 kf = *(const bf16x8*)(qkv + (size_t)(kb * 32 + c * 16 + lc) * QKVN
                                     + DIM + kvh * HDIM + s * 32 + lg * 8);
        sacc[c] = __builtin_amdgcn_mfma_f32_16x16x32_bf16(qf[s], kf, sacc[c], 0, 0, 0);
      }
    }
    float p[2][4];
    int am[2];
#pragma unroll
    for (int c = 0; c < 2; ++c) {
      const int col = kb * 32 + c * 16 + lc;
      am[c] = (prune[col] != 0) ? 1 : 0;
#pragma unroll
      for (int j = 0; j < 4; ++j) {
        const int row = qbase + lg * 4 + j;
        float sv = sacc[c][j] * 0.08838834764831845f;
        p[c][j] = (col <= row) ? sv : -3e38f;
      }
    }
#pragma unroll
    for (int j = 0; j < 4; ++j) {
      float mx = fmaxf(p[0][j], p[1][j]);
      mx = fmaxf(mx, __shfl_xor(mx, 1));
      mx = fmaxf(mx, __shfl_xor(mx, 2));
      mx = fmaxf(mx, __shfl_xor(mx, 4));
      mx = fmaxf(mx, __shfl_xor(mx, 8));
      const float mnew = fmaxf(mrun[j], mx);
      const float scale = __expf(mrun[j] - mnew);
      mrun[j] = mnew;
      const int row = qbase + lg * 4 + j;
      float rs = 0.f;
#pragma unroll
      for (int c = 0; c < 2; ++c) {
        const int col = kb * 32 + c * 16 + lc;
        float e = __expf(p[c][j] - mnew);
        const int keep = (col == row) ? 1 : am[c];
        e = keep ? e : 0.f;
        p[c][j] = e;
        rs += e;
      }
      rs += __shfl_xor(rs, 1);
      rs += __shfl_xor(rs, 2);
      rs += __shfl_xor(rs, 4);
      rs += __shfl_xor(rs, 8);
      lrun[j] = lrun[j] * scale + rs;
#pragma unroll
      for (int df = 0; df < 8; ++df) oacc[df][j] *= scale;
    }
#pragma unroll
    for (int c = 0; c < 2; ++c)
#pragma unroll
      for (int j = 0; j < 4; ++j)
        pw[(lg * 4 + j) * 40 + c * 16 + lc] = (__bf16)p[c][j];
    bf16x8 pa = *(const bf16x8*)(pw + lc * 40 + lg * 8);
#pragma unroll
    for (int df = 0; df < 8; ++df) {
      bf16x8 vf = *(const bf16x8*)(vT + (size_t)(kvh * HDIM + df * 16 + lc) * SEQ + kb * 32 + lg * 8);
      oacc[df] = __builtin_amdgcn_mfma_f32_16x16x32_bf16(pa, vf, oacc[df], 0, 0, 0);
    }
  }
#pragma unroll
  for (int df = 0; df < 8; ++df) {
    const float vs = vsum[kvh * HDIM + df * 16 + lc];
#pragma unroll
    for (int j = 0; j < 4; ++j) {
      const int row = qbase + lg * 4 + j;
      const float denom = lrun[j] + 1e-6f;
      const float val = (oacc[df][j] + 9.765625e-10f * vs) / denom;
      o[(size_t)row * DIM + h * HDIM + df * 16 + lc] = (__bf16)val;
    }
  }
}

// ---------------------------------------------------------------------------
extern "C" void kernel_launch(void* const* d_in, const int* in_sizes, int n_in,
                              void* d_out, int out_size, void* d_ws, size_t ws_size,
                              hipStream_t stream) {
  const float* hidden = (const float*)d_in[0];
  const float* cosb   = (const float*)d_in[1];
  const float* sinb   = (const float*)d_in[2];
  const int*   prune  = (const int*)d_in[3];
  const float* Wq     = (const float*)d_in[4];
  const float* bq     = (const float*)d_in[5];
  const float* Wk     = (const float*)d_in[6];
  const float* bk     = (const float*)d_in[7];
  const float* Wv     = (const float*)d_in[8];
  const float* bv     = (const float*)d_in[9];
  const float* Wo     = (const float*)d_in[10];
  const float* ln1    = (const float*)d_in[11];
  const float* ln2    = (const float*)d_in[12];
  const float* Wg     = (const float*)d_in[13];
  const float* Wu     = (const float*)d_in[14];
  const float* Wd     = (const float*)d_in[15];
  float* out = (float*)d_out;
  char* ws = (char*)d_ws;

  __bf16* WQKVT = (__bf16*)(ws + OFF_WQKVT);
  __bf16* WOT   = (__bf16*)(ws + OFF_WOT);
  __bf16* WGUT  = (__bf16*)(ws + OFF_WGUT);
  __bf16* WDT   = (__bf16*)(ws + OFF_WDT);
  __bf16* XB    = (__bf16*)(ws + OFF_XB);
  __bf16* QKV   = (__bf16*)(ws + OFF_QKV);
  __bf16* VT    = (__bf16*)(ws + OFF_VT);
  float*  VSUMP = (float*)(ws + OFF_VSUMP);
  float*  VSUM  = (float*)(ws + OFF_VSUM);
  __bf16* OB    = (__bf16*)(ws + OFF_OB);
  float*  HB    = (float*)(ws + OFF_HB);
  __bf16* YB    = (__bf16*)(ws + OFF_YB);
  __bf16* PB    = (__bf16*)(ws + OFF_PB);
  float*  PART  = (float*)(ws + OFF_PART);

  // ---- attention branch ----
  transconv_kernel<<<dim3(DIM / 64, DIM / 64), 256, 0, stream>>>(Wq, WQKVT, DIM, DIM, 0);
  transconv_kernel<<<dim3(512 / 64, DIM / 64), 256, 0, stream>>>(Wk, WQKVT + (size_t)DIM * DIM, DIM, 512, 0);
  transconv_kernel<<<dim3(512 / 64, DIM / 64), 256, 0, stream>>>(Wv, WQKVT + (size_t)4096 * DIM, DIM, 512, 0);
  rmsnorm_kernel<<<SEQ, 256, 0, stream>>>(hidden, ln1, XB);

  // qkv = x @ Wqkv + b  (gemm256 split-K 4: 288 blocks) ; fused reduce+rope
  gemm256_kernel<1><<<(SEQ / 256) * (QKVN / 256) * 4, 512, 0, stream>>>(
      XB, WQKVT, PART, SEQ, QKVN, DIM, DIM / 4, SEQ / 256);
  qkv_reduce_rope_kernel<<<SEQ, 256, 0, stream>>>(PART, bq, bk, bv, cosb, sinb, QKV);

  vtrans_kernel<<<dim3(8, NKVH), 256, 0, stream>>>(QKV, VT, VSUMP);
  vsum_reduce_kernel<<<1, 512, 0, stream>>>(VSUMP, VSUM);
  attn_kernel<<<dim3(SEQ / 64, NH), 256, 0, stream>>>(QKV, VT, VSUM, prune, OB);

  // h = hidden + OB @ Wo  (gemm256 split-K 4: 224 blocks = 1 round)
  transconv_kernel<<<dim3(DIM / 64, DIM / 64), 256, 0, stream>>>(Wo, WOT, DIM, DIM, 0);
  gemm256_kernel<1><<<(DIM / 256) * (SEQ / 256) * 4, 512, 0, stream>>>(
      OB, WOT, PART, SEQ, DIM, DIM, DIM / 4, SEQ / 256);
  // fused: h = sum4 + hidden -> HB ; y = rmsnorm(h, ln2) -> YB
  reduce_rms_kernel<<<SEQ, 256, 0, stream>>>(PART, hidden, ln2, HB, YB);

  // gate/up: interleaved WGUT; silu fused -> PB (static grid, XCD swizzle)
  transconv_kernel<<<dim3(IDIM / 64, DIM / 64), 256, 0, stream>>>(Wg, WGUT, DIM, IDIM, 1);
  transconv_kernel<<<dim3(IDIM / 64, DIM / 64), 256, 0, stream>>>(Wu, WGUT, DIM, IDIM, 2);
  gemm256_kernel<0><<<(GUN / 256) * (SEQ / 256), 512, 0, stream>>>(
      YB, WGUT, PB, SEQ, GUN, DIM, DIM, SEQ / 256);

  // out = h + p @ Wd  (gemm256 split-K 4: 224 blocks)
  transconv_kernel<<<dim3(DIM / 64, IDIM / 64), 256, 0, stream>>>(Wd, WDT, IDIM, DIM, 0);
  gemm256_kernel<1><<<(DIM / 256) * (SEQ / 256) * 4, 512, 0, stream>>>(
      PB, WDT, PART, SEQ, DIM, IDIM, IDIM / 4, SEQ / 256);
  reduce_kernel<4, false><<<(SEQ * DIM / 4 + 255) / 256, 256, 0, stream>>>(
      PART, HB, out, DIM, SEQ * DIM / 4);
}

// Round 16
// 909.371 us; speedup vs baseline: 1.0156x; 1.0156x over previous
//
#include <hip/hip_runtime.h>
#include <hip/hip_bf16.h>

// ---------------------------------------------------------------------------
// Qwen2.5-VL decoder layer, MI355X (gfx950)
// B=1, N=1024, D=3584, H=28, KVH=4, HD=128, I=18944
// Round 16: REVERT to R14/R12 best (910 us, twice reproduced). R15's QKV
// split-K 4 regressed (+24 us partial traffic > makespan gain) and is
// dropped. Final config: gemm256 single-barrier-per-phase 8-phase schedule
// (T2 swizzle, counted vmcnt gates, setprio), split-K f32 partials, fused
// epilogues (QKV reduce+bias+rope; Wo reduce+residual+rmsnorm; silu-in-GEMM).
// ---------------------------------------------------------------------------

#define SEQ   1024
#define DIM   3584
#define NH    28
#define NKVH  4
#define HDIM  128
#define IDIM  18944
#define QKVN  4608    // 3584 q + 512 k + 512 v
#define GUN   37888   // 2*18944

typedef __attribute__((ext_vector_type(8))) __bf16 bf16x8;
typedef __attribute__((ext_vector_type(4))) __bf16 bf16x4;
typedef __attribute__((ext_vector_type(4))) float  f32x4;

// ---------------- workspace layout (bytes) ----------------
static constexpr size_t OFF_WQKVT = 0;                                   // [4608][3584] bf16
static constexpr size_t OFF_WOT   = OFF_WQKVT + (size_t)QKVN*DIM*2;      // [3584][3584] bf16
static constexpr size_t OFF_WGUT  = OFF_WOT   + (size_t)DIM*DIM*2;       // [37888][3584] bf16 (interleaved g/u)
static constexpr size_t OFF_WDT   = OFF_WGUT  + (size_t)GUN*DIM*2;       // [3584][18944] bf16
static constexpr size_t OFF_XB    = OFF_WDT   + (size_t)DIM*IDIM*2;      // [1024][3584] bf16
static constexpr size_t OFF_QKV   = OFF_XB    + (size_t)SEQ*DIM*2;       // [1024][4608] bf16
static constexpr size_t OFF_VT    = OFF_QKV   + (size_t)SEQ*QKVN*2;      // [4][128][1024] bf16
static constexpr size_t OFF_VSUMP = OFF_VT    + (size_t)NKVH*HDIM*SEQ*2; // [4][8][128] f32
static constexpr size_t OFF_VSUM  = OFF_VSUMP + 4*8*128*4;               // [4][128] f32
static constexpr size_t OFF_BQKV  = OFF_VSUM  + 4*128*4;                 // [4608] f32
static constexpr size_t OFF_OB    = OFF_BQKV  + (size_t)QKVN*4;          // [1024][3584] bf16
static constexpr size_t OFF_HB    = OFF_OB    + (size_t)SEQ*DIM*2;       // [1024][3584] f32
static constexpr size_t OFF_YB    = OFF_HB    + (size_t)SEQ*DIM*4;       // [1024][3584] bf16
static constexpr size_t OFF_GU    = OFF_YB    + (size_t)SEQ*DIM*2;       // 77.6 MB scratch region
static constexpr size_t OFF_PB    = OFF_GU    + (size_t)SEQ*GUN*2;       // [1024][18944] bf16
// split-K f32 partials live in the (always dead) GU region: max 58.7 MB < 77.6.
static constexpr size_t OFF_PART  = OFF_GU;

// async global->LDS, 16B per lane. lds ptr must be wave-uniform; HW writes
// lane l's 16B to ldsbase + l*16. global ptr is per-lane.
#define GLL16(gp, lp)                                                        \
  __builtin_amdgcn_global_load_lds(                                         \
      (const __attribute__((address_space(1))) void*)(gp),                  \
      (__attribute__((address_space(3))) void*)(lp), 16, 0, 0)

#define BAR    asm volatile("s_barrier" ::: "memory")
#define LGKM0  asm volatile("s_waitcnt lgkmcnt(0)" ::: "memory")
#define VM4    asm volatile("s_waitcnt vmcnt(4)" ::: "memory")

// ---------------- weight transpose + fp32->bf16 ----------------
// mode 0: out row = n.  mode 1/2: interleaved gate/up layout
// (phys row = (n>>4)*32 + (n&15) + (mode==2 ? 16 : 0)).
__global__ __launch_bounds__(256) void transconv_kernel(
    const float* __restrict__ W, __bf16* __restrict__ WT, int K, int N, int mode)
{
  __shared__ __bf16 t[64][72];
  const int tid = threadIdx.x;
  const int k0 = blockIdx.y * 64, n0 = blockIdx.x * 64;
#pragma unroll
  for (int it = 0; it < 4; ++it) {
    int idx = it * 256 + tid;
    int r = idx >> 4, c4 = idx & 15;
    float4 v = *(const float4*)(W + (size_t)(k0 + r) * N + n0 + c4 * 4);
    t[r][c4 * 4 + 0] = (__bf16)v.x;
    t[r][c4 * 4 + 1] = (__bf16)v.y;
    t[r][c4 * 4 + 2] = (__bf16)v.z;
    t[r][c4 * 4 + 3] = (__bf16)v.w;
  }
  __syncthreads();
#pragma unroll
  for (int it = 0; it < 2; ++it) {
    int idx = it * 256 + tid;
    int r = idx >> 3, c8 = idx & 7;
    bf16x8 o;
#pragma unroll
    for (int i = 0; i < 8; ++i) o[i] = t[c8 * 8 + i][r];
    const int nlog = n0 + r;
    const int orow = (mode == 0) ? nlog
                   : ((nlog >> 4) << 5) + ((mode == 2) ? 16 : 0) + (nlog & 15);
    *(bf16x8*)(WT + (size_t)orow * K + k0 + c8 * 8) = o;
  }
}

// ---------------- bias concat ----------------
__global__ __launch_bounds__(256) void pack_bias_kernel(
    const float* __restrict__ bq, const float* __restrict__ bk,
    const float* __restrict__ bv, float* __restrict__ out)
{
  int i = blockIdx.x * 256 + threadIdx.x;
  if (i < DIM) out[i] = bq[i];
  else if (i < DIM + 512) out[i] = bk[i - DIM];
  else if (i < QKVN) out[i] = bv[i - DIM - 512];
}

// ---------------- RMSNorm (fp32 in, bf16 out) ----------------
__global__ __launch_bounds__(256) void rmsnorm_kernel(
    const float* __restrict__ in, const float* __restrict__ w,
    __bf16* __restrict__ out)
{
  const int row = blockIdx.x;
  const int t = threadIdx.x;
  const float* x = in + (size_t)row * DIM;
  float4 v[4];
  float ss = 0.f;
#pragma unroll
  for (int i = 0; i < 4; ++i) {
    int idx = t + i * 256;
    if (idx < 896) {
      v[i] = ((const float4*)x)[idx];
      ss += v[i].x * v[i].x + v[i].y * v[i].y + v[i].z * v[i].z + v[i].w * v[i].w;
    }
  }
#pragma unroll
  for (int m = 1; m < 64; m <<= 1) ss += __shfl_xor(ss, m);
  __shared__ float red[4];
  if ((t & 63) == 0) red[t >> 6] = ss;
  __syncthreads();
  float tot = red[0] + red[1] + red[2] + red[3];
  float rs = rsqrtf(tot / (float)DIM + 1e-6f);
#pragma unroll
  for (int i = 0; i < 4; ++i) {
    int idx = t + i * 256;
    if (idx < 896) {
      float4 wv = ((const float4*)w)[idx];
      bf16x4 o;
      o[0] = (__bf16)(v[i].x * rs * wv.x);
      o[1] = (__bf16)(v[i].y * rs * wv.y);
      o[2] = (__bf16)(v[i].z * rs * wv.z);
      o[3] = (__bf16)(v[i].w * rs * wv.w);
      *(bf16x4*)(out + (size_t)row * DIM + idx * 4) = o;
    }
  }
}

// ---------------- split-K reduce epilogues ---------------------------------
template<int S, bool BF16OUT, bool BIAS>
__global__ __launch_bounds__(256) void reduce_kernel(
    const float* __restrict__ part, const float* __restrict__ resid,
    const float* __restrict__ bias, void* __restrict__ out, int N, int MN4)
{
  const int i4 = blockIdx.x * 256 + threadIdx.x;
  if (i4 >= MN4) return;
  const size_t base = (size_t)i4 * 4;
  f32x4 s = *(const f32x4*)(part + base);
#pragma unroll
  for (int k = 1; k < S; ++k)
    s += *(const f32x4*)(part + (size_t)k * MN4 * 4 + base);
  if (BIAS) {
    const int col = (int)(base % N);
    s += *(const f32x4*)(bias + col);
  }
  if (resid != nullptr) s += *(const f32x4*)(resid + base);
  if (BF16OUT) {
    bf16x4 o;
#pragma unroll
    for (int j = 0; j < 4; ++j) o[j] = (__bf16)s[j];
    *(bf16x4*)((__bf16*)out + base) = o;
  } else {
    *(f32x4*)((float*)out + base) = s;
  }
}

// ---------------- fused QKV split-K(2) reduce + bias + mRoPE ---------------
__global__ __launch_bounds__(256) void qkv_reduce_rope_kernel(
    const float* __restrict__ part, const float* __restrict__ bias,
    const float* __restrict__ cosb, const float* __restrict__ sinb,
    __bf16* __restrict__ qkv)
{
  const int n = blockIdx.x;
  const int t = threadIdx.x;
  const size_t rb = (size_t)n * QKVN;
  const size_t slab = (size_t)SEQ * QKVN;

  const int head = t >> 3;
  const int d0 = (t & 7) * 8;
  const int col = (head < NH) ? head * HDIM + d0 : DIM + (head - NH) * HDIM + d0;

  float lo[8], hi[8];
#pragma unroll
  for (int j = 0; j < 8; j += 4) {
    f32x4 a  = *(const f32x4*)(part + rb + col + j);
    f32x4 b  = *(const f32x4*)(part + slab + rb + col + j);
    f32x4 bi = *(const f32x4*)(bias + col + j);
    f32x4 a2  = *(const f32x4*)(part + rb + col + 64 + j);
    f32x4 b2  = *(const f32x4*)(part + slab + rb + col + 64 + j);
    f32x4 bi2 = *(const f32x4*)(bias + col + 64 + j);
#pragma unroll
    for (int i = 0; i < 4; ++i) {
      lo[j + i] = a[i] + b[i] + bi[i];
      hi[j + i] = a2[i] + b2[i] + bi2[i];
    }
  }
  bf16x8 olo, ohi;
#pragma unroll
  for (int j = 0; j < 8; ++j) {
    const int d = d0 + j;
    const int src = (d < 16) ? 0 : (d < 40) ? 1 : 2;   // same src for d and d+64
    const float* cb = cosb + ((size_t)src * SEQ + n) * HDIM;
    const float* sb = sinb + ((size_t)src * SEQ + n) * HDIM;
    const float c0 = cb[d], s0 = sb[d];
    const float c1 = cb[d + 64], s1 = sb[d + 64];
    olo[j] = (__bf16)(lo[j] * c0 - hi[j] * s0);
    ohi[j] = (__bf16)(hi[j] * c1 + lo[j] * s1);
  }
  *(bf16x8*)(qkv + rb + col) = olo;
  *(bf16x8*)(qkv + rb + col + 64) = ohi;

  // v: cols 4096 + 2t, 2t+1 (no rope)
  {
    const int vc = 4096 + t * 2;
    float2 a  = *(const float2*)(part + rb + vc);
    float2 b  = *(const float2*)(part + slab + rb + vc);
    float2 bi = *(const float2*)(bias + vc);
    qkv[rb + vc]     = (__bf16)(a.x + b.x + bi.x);
    qkv[rb + vc + 1] = (__bf16)(a.y + b.y + bi.y);
  }
}

// ---------------- fused split-K(4) reduce + residual + RMSNorm -------------
__global__ __launch_bounds__(256) void reduce_rms_kernel(
    const float* __restrict__ part, const float* __restrict__ resid,
    const float* __restrict__ w, float* __restrict__ hout,
    __bf16* __restrict__ yout)
{
  const int row = blockIdx.x;
  const int t = threadIdx.x;
  const size_t base = (size_t)row * DIM;
  const size_t slab = (size_t)SEQ * DIM;
  f32x4 v[4];
  float ss = 0.f;
#pragma unroll
  for (int i = 0; i < 4; ++i) {
    int idx = t + i * 256;
    if (idx < 896) {
      f32x4 s = *(const f32x4*)(part + base + idx * 4);
      s += *(const f32x4*)(part + slab + base + idx * 4);
      s += *(const f32x4*)(part + 2 * slab + base + idx * 4);
      s += *(const f32x4*)(part + 3 * slab + base + idx * 4);
      s += *(const f32x4*)(resid + base + idx * 4);
      v[i] = s;
      ss += s[0] * s[0] + s[1] * s[1] + s[2] * s[2] + s[3] * s[3];
      *(f32x4*)(hout + base + idx * 4) = s;
    }
  }
#pragma unroll
  for (int m = 1; m < 64; m <<= 1) ss += __shfl_xor(ss, m);
  __shared__ float red[4];
  if ((t & 63) == 0) red[t >> 6] = ss;
  __syncthreads();
  float tot = red[0] + red[1] + red[2] + red[3];
  float rs = rsqrtf(tot / (float)DIM + 1e-6f);
#pragma unroll
  for (int i = 0; i < 4; ++i) {
    int idx = t + i * 256;
    if (idx < 896) {
      f32x4 wv = *(const f32x4*)(w + idx * 4);
      bf16x4 o;
#pragma unroll
      for (int j = 0; j < 4; ++j) o[j] = (__bf16)(v[i][j] * rs * wv[j]);
      *(bf16x4*)(yout + base + idx * 4) = o;
    }
  }
}

// ---------------- 256x256 8-phase GEMM, 1 barrier per phase ----------------
// Interval: {LGKM0; MFMA(q); RD(q+1); STG; [VM4 then RD at gates]; BAR}.
// Same-interval STG/RD regions disjoint (verified per phase); VM4 gates
// drain exactly the to-be-read tile (newest-4 = the two just-issued pairs).
// EPI 0: gate/up interleaved -> silu(g)*u -> bf16 [M][N/2] out.
// EPI 1: f32 split-K partial out (OUT + ks*M*N).
template<int EPI>
__global__ __launch_bounds__(512, 1) void gemm256_kernel(
    const __bf16* __restrict__ A, const __bf16* __restrict__ BT,
    void* __restrict__ OUT, int M, int N, int K, int Kc, int gridY)
{
  __shared__ int4 lds4[8192];            // 128 KB
  char* ldsc = (char*)lds4;
  const int tid = threadIdx.x;
  const int l = tid & 63, w = tid >> 6;
  const int wr = w >> 2, wc = w & 3;
  const int lg = l >> 4, lc = l & 15;

  const int nwg = gridDim.x;
  const int bq8 = nwg >> 3, br8 = nwg & 7;
  const int xcd = blockIdx.x & 7, bidx = blockIdx.x >> 3;
  const int wg = (xcd < br8 ? xcd * (bq8 + 1) : br8 * (bq8 + 1) + (xcd - br8) * bq8) + bidx;
  const int ntn = N >> 8;
  const int wg2 = wg / gridY;
  const int row0 = (wg % gridY) * 256;
  const int col0 = (wg2 % ntn) * 256;
  const int ks_ = wg2 / ntn;
  const int kbase = ks_ * Kc;

  size_t aoffj[2], boffj[2];
  int dstj[2];
#pragma unroll
  for (int j = 0; j < 2; ++j) {
    const int c = (j * 8 + w) * 64 + l;
    const int r = c >> 3, p = c & 7;
    const int b = p ^ (r & 7);
    aoffj[j] = (size_t)(row0 + r) * K + kbase + b * 8;
    boffj[j] = (size_t)(col0 + r) * K + kbase + b * 8;
    dstj[j] = (j * 8 + w) * 1024;
  }

#define STG_A(U, KT, BUFB) do {                                              \
    GLL16(A + aoffj[0] + (size_t)(U) * 128 * K + (size_t)(KT) * 64,          \
          ldsc + (BUFB) + (U) * 16384 + dstj[0]);                            \
    GLL16(A + aoffj[1] + (size_t)(U) * 128 * K + (size_t)(KT) * 64,          \
          ldsc + (BUFB) + (U) * 16384 + dstj[1]); } while (0)
#define STG_B(U, KT, BUFB) do {                                              \
    GLL16(BT + boffj[0] + (size_t)(U) * 128 * K + (size_t)(KT) * 64,         \
          ldsc + (BUFB) + 32768 + (U) * 16384 + dstj[0]);                    \
    GLL16(BT + boffj[1] + (size_t)(U) * 128 * K + (size_t)(KT) * 64,         \
          ldsc + (BUFB) + 32768 + (U) * 16384 + dstj[1]); } while (0)

  const int sw = lc & 7;
  const int rdA = (wr * 128 + lc) * 128;
  const int rdB = 32768 + (wc * 64 + lc) * 128;
  const int sk0 = (lg ^ sw) * 16;
  const int sk1 = ((4 | lg) ^ sw) * 16;

  f32x4 acc[8][4] = {};
  bf16x8 af[4][2], bfr[4][2];

#define RD_A4(MH, BUFB) do { _Pragma("unroll")                               \
    for (int mm = 0; mm < 4; ++mm) {                                         \
      af[mm][0] = *(const bf16x8*)(ldsc + (BUFB) + rdA + ((MH) * 4 + mm) * 2048 + sk0); \
      af[mm][1] = *(const bf16x8*)(ldsc + (BUFB) + rdA + ((MH) * 4 + mm) * 2048 + sk1); } } while (0)
#define RD_B2(NL, BUFB) do { _Pragma("unroll")                               \
    for (int nn = 0; nn < 2; ++nn) {                                         \
      bfr[(NL) + nn][0] = *(const bf16x8*)(ldsc + (BUFB) + rdB + ((NL) + nn) * 2048 + sk0); \
      bfr[(NL) + nn][1] = *(const bf16x8*)(ldsc + (BUFB) + rdB + ((NL) + nn) * 2048 + sk1); } } while (0)

#define MFMA16(MH, NL) do { _Pragma("unroll")                                \
    for (int mm = 0; mm < 4; ++mm) { _Pragma("unroll")                       \
      for (int nn = 0; nn < 2; ++nn) {                                       \
        acc[(MH)*4+mm][(NL)+nn] = __builtin_amdgcn_mfma_f32_16x16x32_bf16(   \
            af[mm][0], bfr[(NL)+nn][0], acc[(MH)*4+mm][(NL)+nn], 0, 0, 0);   \
        acc[(MH)*4+mm][(NL)+nn] = __builtin_amdgcn_mfma_f32_16x16x32_bf16(   \
            af[mm][1], bfr[(NL)+nn][1], acc[(MH)*4+mm][(NL)+nn], 0, 0, 0); } } } while (0)

#define DO_MFMA(MH, NL)                                                      \
    __builtin_amdgcn_s_setprio(1); MFMA16(MH, NL);                           \
    __builtin_amdgcn_s_setprio(0)

  // prologue: E(tile0) full + O(tile1) B halves; VM4 drains E (own-wave),
  // BAR makes it block-wide; then prefetch q1(E).
  STG_B(0, 0, 0); STG_B(1, 0, 0); STG_A(0, 0, 0); STG_A(1, 0, 0);
  STG_B(0, 1, 65536); STG_B(1, 1, 65536);
  VM4;
  BAR;
  RD_A4(0, 0); RD_B2(0, 0);

  const int T = Kc >> 6;                 // even for all call sites
#pragma unroll 1
  for (int i = 0; i < (T >> 1); ++i) {
    const int t1 = 2 * i + 1;
    const int se = (2 * i + 2 < T) ? 2 * i + 2 : 2 * i;   // E next (dummy=cur)
    const int so = (2 * i + 3 < T) ? 2 * i + 3 : t1;      // O next
    // I1: MFMA q1(E); read q2(E); stage O.A0(t1)
    LGKM0; DO_MFMA(0, 0); RD_B2(2, 0); STG_A(0, t1, 65536); BAR;
    // I2: MFMA q2(E); read q3(E); stage O.A1(t1)
    LGKM0; DO_MFMA(0, 2); RD_A4(1, 0); STG_A(1, t1, 65536); BAR;
    // I3: MFMA q3(E); stage E.B0(se)   [E.B last read completed at I2 LGKM0]
    LGKM0; DO_MFMA(1, 2); STG_B(0, se, 0); BAR;
    // I4: MFMA q4(E, reg-only); stage E.B1(se); GATE O(t1); read q1(O)
    DO_MFMA(1, 0); STG_B(1, se, 0); VM4; RD_A4(0, 65536); RD_B2(0, 65536); BAR;
    // I5: MFMA q1(O); read q2(O); stage E.A0(se)
    LGKM0; DO_MFMA(0, 0); RD_B2(2, 65536); STG_A(0, se, 0); BAR;
    // I6: MFMA q2(O); read q3(O); stage E.A1(se)
    LGKM0; DO_MFMA(0, 2); RD_A4(1, 65536); STG_A(1, se, 0); BAR;
    // I7: MFMA q3(O); stage O.B0(so)
    LGKM0; DO_MFMA(1, 2); STG_B(0, so, 65536); BAR;
    // I8: MFMA q4(O); stage O.B1(so); GATE E(se); read q1(E next)
    DO_MFMA(1, 0); STG_B(1, so, 65536); VM4; RD_A4(0, 0); RD_B2(0, 0); BAR;
  }
  asm volatile("s_waitcnt vmcnt(0)" ::: "memory");
  LGKM0;                                 // drain trailing prefetch reads

  if (EPI == 0) {
    // interleaved g/u: fragment n even = gate cols, n odd = up cols (same q)
    __bf16* PBo = (__bf16*)OUT;
    const int id = N >> 1;               // 18944
    const int baseq = (col0 + wc * 64) >> 5;
#pragma unroll
    for (int m = 0; m < 8; ++m) {
#pragma unroll
      for (int p = 0; p < 2; ++p) {
        const int gcol = (baseq + p) * 16 + lc;
#pragma unroll
        for (int j = 0; j < 4; ++j) {
          const int row = row0 + wr * 128 + m * 16 + lg * 4 + j;
          const float g = acc[m][2 * p][j];
          const float u = acc[m][2 * p + 1][j];
          const float s = g / (1.f + __expf(-g));
          PBo[(size_t)row * id + gcol] = (__bf16)(s * u);
        }
      }
    }
  } else {
    float* P = (float*)OUT + (size_t)ks_ * M * N;
#pragma unroll
    for (int m = 0; m < 8; ++m)
#pragma unroll
      for (int n = 0; n < 4; ++n)
#pragma unroll
        for (int j = 0; j < 4; ++j)
          P[(size_t)(row0 + wr * 128 + m * 16 + lg * 4 + j) * N
            + (col0 + wc * 64 + n * 16 + lc)] = acc[m][n][j];
  }
#undef STG_A
#undef STG_B
#undef RD_A4
#undef RD_B2
#undef MFMA16
#undef DO_MFMA
}

// ---------------- V transpose [n][d] -> [d][n], plus column sums -----------
__global__ __launch_bounds__(256) void vtrans_kernel(
    const __bf16* __restrict__ qkv, __bf16* __restrict__ vT,
    float* __restrict__ vsump)
{
  __shared__ __bf16 t[128][132];
  const int nt = blockIdx.x, kvh = blockIdx.y;
  const int n0 = nt * 128;
  const int tid = threadIdx.x;
#pragma unroll
  for (int it = 0; it < 8; ++it) {
    int idx = it * 256 + tid;
    int nl = idx >> 4, c8 = idx & 15;
    bf16x8 v = *(const bf16x8*)(qkv + (size_t)(n0 + nl) * QKVN + 4096 + kvh * HDIM + c8 * 8);
#pragma unroll
    for (int i = 0; i < 8; ++i) t[nl][c8 * 8 + i] = v[i];
  }
  __syncthreads();
#pragma unroll
  for (int it = 0; it < 8; ++it) {
    int idx = it * 256 + tid;
    int d = idx >> 4, c8 = idx & 15;
    bf16x8 o;
#pragma unroll
    for (int i = 0; i < 8; ++i) o[i] = t[c8 * 8 + i][d];
    *(bf16x8*)(vT + (size_t)(kvh * HDIM + d) * SEQ + n0 + c8 * 8) = o;
  }
  if (tid < 128) {
    float s = 0.f;
    for (int nl = 0; nl < 128; ++nl) s += (float)t[nl][tid];
    vsump[(size_t)(kvh * 8 + nt) * 128 + tid] = s;
  }
}

__global__ __launch_bounds__(512) void vsum_reduce_kernel(
    const float* __restrict__ vsump, float* __restrict__ vsum)
{
  const int idx = threadIdx.x;
  const int kvh = idx >> 7, d = idx & 127;
  float s = 0.f;
#pragma unroll
  for (int nt = 0; nt < 8; ++nt) s += vsump[(size_t)(kvh * 8 + nt) * 128 + d];
  vsum[idx] = s;
}

// ---------------- attention -------------------------------------------------
__global__ __launch_bounds__(256) void attn_kernel(
    const __bf16* __restrict__ qkv, const __bf16* __restrict__ vT,
    const float* __restrict__ vsum, const int* __restrict__ prune,
    __bf16* __restrict__ o)
{
  __shared__ __bf16 plds[4 * 16 * 40];
  const int tid = threadIdx.x;
  const int l = tid & 63, w = tid >> 6;
  const int h = blockIdx.y;
  const int kvh = h / 7;
  const int qt = blockIdx.x;
  const int qbase = qt * 64 + w * 16;
  const int lg = l >> 4, lc = l & 15;
  __bf16* pw = plds + w * (16 * 40);

  bf16x8 qf[4];
#pragma unroll
  for (int s = 0; s < 4; ++s)
    qf[s] = *(const bf16x8*)(qkv + (size_t)(qbase + lc) * QKVN + h * HDIM + s * 32 + lg * 8);

  f32x4 oacc[8] = {};
  float mrun[4] = {-3e38f, -3e38f, -3e38f, -3e38f};
  float lrun[4] = {0.f, 0.f, 0.f, 0.f};

  const int kbEnd = ((qbase + 15) >> 5) + 1;
  for (int kb = 0; kb < kbEnd; ++kb) {
    f32x4 sacc[2] = {};
#pragma unroll
    for (int s = 0; s < 4; ++s) {
#pragma unroll
      for (int c = 0; c < 2; ++c) {
        bf16x8 kf = *(const bf16x8*)(qkv + (size_t)(kb * 32 + c * 16 + lc) * QKVN
                                     + DIM + kvh * HDIM + s * 32 + lg * 8);
        sacc[c] = __builtin_amdgcn_mfma_f32_16x16x32_bf16(qf[s], kf, sacc[c], 0, 0, 0);
      }
    }
    float p[2][4];
    int am[2];
#pragma unroll
    for (int c = 0; c < 2; ++c) {
      const int col = kb * 32 + c * 16 + lc;
      am[c] = (prune[col] != 0) ? 1 : 0;
#pragma unroll
      for (int j = 0; j < 4; ++j) {
        const int row = qbase + lg * 4 + j;
        float sv = sacc[c][j] * 0.08838834764831845f;
        p[c][j] = (col <= row) ? sv : -3e38f;
      }
    }
#pragma unroll
    for (int j = 0; j < 4; ++j) {
      float mx = fmaxf(p[0][j], p[1][j]);
      mx = fmaxf(mx, __shfl_xor(mx, 1));
      mx = fmaxf(mx, __shfl_xor(mx, 2));
      mx = fmaxf(mx, __shfl_xor(mx, 4));
      mx = fmaxf(mx, __shfl_xor(mx, 8));
      const float mnew = fmaxf(mrun[j], mx);
      const float scale = __expf(mrun[j] - mnew);
      mrun[j] = mnew;
      const int row = qbase + lg * 4 + j;
      float rs = 0.f;
#pragma unroll
      for (int c = 0; c < 2; ++c) {
        const int col = kb * 32 + c * 16 + lc;
        float e = __expf(p[c][j] - mnew);
        const int keep = (col == row) ? 1 : am[c];
        e = keep ? e : 0.f;
        p[c][j] = e;
        rs += e;
      }
      rs += __shfl_xor(rs, 1);
      rs += __shfl_xor(rs, 2);
      rs += __shfl_xor(rs, 4);
      rs += __shfl_xor(rs, 8);
      lrun[j] = lrun[j] * scale + rs;
#pragma unroll
      for (int df = 0; df < 8; ++df) oacc[df][j] *= scale;
    }
#pragma unroll
    for (int c = 0; c < 2; ++c)
#pragma unroll
      for (int j = 0; j < 4; ++j)
        pw[(lg * 4 + j) * 40 + c * 16 + lc] = (__bf16)p[c][j];
    bf16x8 pa = *(const bf16x8*)(pw + lc * 40 + lg * 8);
#pragma unroll
    for (int df = 0; df < 8; ++df) {
      bf16x8 vf = *(const bf16x8*)(vT + (size_t)(kvh * HDIM + df * 16 + lc) * SEQ + kb * 32 + lg * 8);
      oacc[df] = __builtin_amdgcn_mfma_f32_16x16x32_bf16(pa, vf, oacc[df], 0, 0, 0);
    }
  }
#pragma unroll
  for (int df = 0; df < 8; ++df) {
    const float vs = vsum[kvh * HDIM + df * 16 + lc];
#pragma unroll
    for (int j = 0; j < 4; ++j) {
      const int row = qbase + lg * 4 + j;
      const float denom = lrun[j] + 1e-6f;
      const float val = (oacc[df][j] + 9.765625e-10f * vs) / denom;
      o[(size_t)row * DIM + h * HDIM + df * 16 + lc] = (__bf16)val;
    }
  }
}

// ---------------------------------------------------------------------------
extern "C" void kernel_launch(void* const* d_in, const int* in_sizes, int n_in,
                              void* d_out, int out_size, void* d_ws, size_t ws_size,
                              hipStream_t stream) {
  const float* hidden = (const float*)d_in[0];
  const float* cosb   = (const float*)d_in[1];
  const float* sinb   = (const float*)d_in[2];
  const int*   prune  = (const int*)d_in[3];
  const float* Wq     = (const float*)d_in[4];
  const float* bq     = (const float*)d_in[5];
  const float* Wk     = (const float*)d_in[6];
  const float* bk     = (const float*)d_in[7];
  const float* Wv     = (const float*)d_in[8];
  const float* bv     = (const float*)d_in[9];
  const float* Wo     = (const float*)d_in[10];
  const float* ln1    = (const float*)d_in[11];
  const float* ln2    = (const float*)d_in[12];
  const float* Wg     = (const float*)d_in[13];
  const float* Wu     = (const float*)d_in[14];
  const float* Wd     = (const float*)d_in[15];
  float* out = (float*)d_out;
  char* ws = (char*)d_ws;

  __bf16* WQKVT = (__bf16*)(ws + OFF_WQKVT);
  __bf16* WOT   = (__bf16*)(ws + OFF_WOT);
  __bf16* WGUT  = (__bf16*)(ws + OFF_WGUT);
  __bf16* WDT   = (__bf16*)(ws + OFF_WDT);
  __bf16* XB    = (__bf16*)(ws + OFF_XB);
  __bf16* QKV   = (__bf16*)(ws + OFF_QKV);
  __bf16* VT    = (__bf16*)(ws + OFF_VT);
  float*  VSUMP = (float*)(ws + OFF_VSUMP);
  float*  VSUM  = (float*)(ws + OFF_VSUM);
  float*  BQKV  = (float*)(ws + OFF_BQKV);
  __bf16* OB    = (__bf16*)(ws + OFF_OB);
  float*  HB    = (float*)(ws + OFF_HB);
  __bf16* YB    = (__bf16*)(ws + OFF_YB);
  __bf16* PB    = (__bf16*)(ws + OFF_PB);
  float*  PART  = (float*)(ws + OFF_PART);

  // ---- attention branch ----
  transconv_kernel<<<dim3(DIM / 64, DIM / 64), 256, 0, stream>>>(Wq, WQKVT, DIM, DIM, 0);
  transconv_kernel<<<dim3(512 / 64, DIM / 64), 256, 0, stream>>>(Wk, WQKVT + (size_t)DIM * DIM, DIM, 512, 0);
  transconv_kernel<<<dim3(512 / 64, DIM / 64), 256, 0, stream>>>(Wv, WQKVT + (size_t)4096 * DIM, DIM, 512, 0);
  pack_bias_kernel<<<QKVN / 256, 256, 0, stream>>>(bq, bk, bv, BQKV);
  rmsnorm_kernel<<<SEQ, 256, 0, stream>>>(hidden, ln1, XB);

  // qkv = x @ Wqkv + b  (gemm256 split-K 2: 144 blocks) ; fused reduce+rope
  gemm256_kernel<1><<<(SEQ / 256) * (QKVN / 256) * 2, 512, 0, stream>>>(
      XB, WQKVT, PART, SEQ, QKVN, DIM, DIM / 2, SEQ / 256);
  qkv_reduce_rope_kernel<<<SEQ, 256, 0, stream>>>(PART, BQKV, cosb, sinb, QKV);

  vtrans_kernel<<<dim3(8, NKVH), 256, 0, stream>>>(QKV, VT, VSUMP);
  vsum_reduce_kernel<<<1, 512, 0, stream>>>(VSUMP, VSUM);
  attn_kernel<<<dim3(SEQ / 64, NH), 256, 0, stream>>>(QKV, VT, VSUM, prune, OB);

  // h = hidden + OB @ Wo  (gemm256 split-K 4: 224 blocks = 1 round)
  transconv_kernel<<<dim3(DIM / 64, DIM / 64), 256, 0, stream>>>(Wo, WOT, DIM, DIM, 0);
  gemm256_kernel<1><<<(DIM / 256) * (SEQ / 256) * 4, 512, 0, stream>>>(
      OB, WOT, PART, SEQ, DIM, DIM, DIM / 4, SEQ / 256);
  // fused: h = sum4 + hidden -> HB ; y = rmsnorm(h, ln2) -> YB
  reduce_rms_kernel<<<SEQ, 256, 0, stream>>>(PART, hidden, ln2, HB, YB);

  // gate/up: interleaved WGUT; silu fused -> PB (static grid, XCD swizzle)
  transconv_kernel<<<dim3(IDIM / 64, DIM / 64), 256, 0, stream>>>(Wg, WGUT, DIM, IDIM, 1);
  transconv_kernel<<<dim3(IDIM / 64, DIM / 64), 256, 0, stream>>>(Wu, WGUT, DIM, IDIM, 2);
  gemm256_kernel<0><<<(GUN / 256) * (SEQ / 256), 512, 0, stream>>>(
      YB, WGUT, PB, SEQ, GUN, DIM, DIM, SEQ / 256);

  // out = h + p @ Wd  (gemm256 split-K 4: 224 blocks)
  transconv_kernel<<<dim3(DIM / 64, IDIM / 64), 256, 0, stream>>>(Wd, WDT, IDIM, DIM, 0);
  gemm256_kernel<1><<<(DIM / 256) * (SEQ / 256) * 4, 512, 0, stream>>>(
      PB, WDT, PART, SEQ, DIM, IDIM, IDIM / 4, SEQ / 256);
  reduce_kernel<4, false, false><<<(SEQ * DIM / 4 + 255) / 256, 256, 0, stream>>>(
      PART, HB, nullptr, out, DIM, SEQ * DIM / 4);
}